// Round 2
// baseline (523.917 us; speedup 1.0000x reference)
//
#include <hip/hip_runtime.h>
#include <cstdint>
#include <cstddef>

// Problem constants (from reference setup_inputs)
#define BN 16     // batch
#define CC 256    // channels
#define CKD 32    // q/k channels
#define NN 4096   // H*W

typedef __attribute__((ext_vector_type(8))) short s8v;    // 8 bf16 = 4 VGPRs (MFMA A/B frag)
typedef __attribute__((ext_vector_type(4))) float f4v;    // MFMA C/D frag
typedef __attribute__((ext_vector_type(4))) unsigned int u4v;
typedef unsigned short ushort_t;

#define L2E 1.44269504088896340736f

__device__ __forceinline__ ushort_t f2bf(float f) {
    union { float f; uint32_t u; } v; v.f = f;
    uint32_t u = v.u + 0x7FFFu + ((v.u >> 16) & 1u);  // RNE
    return (ushort_t)(u >> 16);
}
__device__ __forceinline__ uint32_t fbits(float f) {
    union { float f; uint32_t u; } v; v.f = f; return v.u;
}
// raw v_exp_f32: computes 2^x (q is pre-scaled by log2e in proj)
__device__ __forceinline__ float exp2_hw(float x) {
    float r; asm("v_exp_f32 %0, %1" : "=v"(r) : "v"(x)); return r;
}
// pack two floats to (bf16(lo) | bf16(hi)<<16), truncation (v2-verified pattern)
__device__ __forceinline__ uint32_t pkbf(float lo, float hi) {
    return __builtin_amdgcn_perm(fbits(hi), fbits(lo), 0x07060302u);
}

// ---------------- fused q/k/v projection as one MFMA GEMM (unchanged from v2) ----------------
__global__ __launch_bounds__(256) void proj_all(
    const float* __restrict__ x,
    const float* __restrict__ Wq, const float* __restrict__ bq,
    const float* __restrict__ Wk, const float* __restrict__ bk,
    const float* __restrict__ Wv, const float* __restrict__ bv,
    ushort_t* __restrict__ qw, ushort_t* __restrict__ kw, ushort_t* __restrict__ vw)
{
    __shared__ __align__(16) ushort_t As[64 * 264];

    int b  = blockIdx.z;
    int m0 = blockIdx.y * 64;
    int n0 = blockIdx.x * 128;
    int tid = threadIdx.x;
    int wave = tid >> 6, lane = tid & 63;
    int lq = lane & 15, quad = lane >> 4;

    {
        int arow = tid >> 2;
        int kseg = (tid & 3) * 64;
        int am = m0 + arow;
        const float* wrow;
        if (am < 32)       wrow = Wq + (size_t)am * CC;
        else if (am < 64)  wrow = Wk + (size_t)(am - 32) * CC;
        else               wrow = Wv + (size_t)(am - 64) * CC;
#pragma unroll
        for (int g = 0; g < 8; g++) {
            f4v f0 = *reinterpret_cast<const f4v*>(wrow + kseg + g * 8);
            f4v f1 = *reinterpret_cast<const f4v*>(wrow + kseg + g * 8 + 4);
            s8v p;
            p[0] = (short)f2bf(f0[0]); p[1] = (short)f2bf(f0[1]);
            p[2] = (short)f2bf(f0[2]); p[3] = (short)f2bf(f0[3]);
            p[4] = (short)f2bf(f1[0]); p[5] = (short)f2bf(f1[1]);
            p[6] = (short)f2bf(f1[2]); p[7] = (short)f2bf(f1[3]);
            *reinterpret_cast<s8v*>(&As[arow * 264 + kseg + g * 8]) = p;
        }
    }
    __syncthreads();

    f4v acc[4][2];
#pragma unroll
    for (int i = 0; i < 4; i++)
#pragma unroll
        for (int j = 0; j < 2; j++) acc[i][j] = (f4v){0.f, 0.f, 0.f, 0.f};

    const float* xb = x + (size_t)b * CC * NN + n0 + wave * 32 + lq;

#pragma unroll 2
    for (int h = 0; h < 8; h++) {
        s8v bb[2];
#pragma unroll
        for (int nt = 0; nt < 2; nt++) {
            const float* src = xb + (size_t)(h * 32 + quad * 8) * NN + nt * 16;
            float t0 = src[0 * NN];
            float t1 = src[1 * NN];
            float t2 = src[2 * NN];
            float t3 = src[3 * NN];
            float t4 = src[4 * NN];
            float t5 = src[5 * NN];
            float t6 = src[6 * NN];
            float t7 = src[7 * NN];
            s8v p;
            p[0] = (short)f2bf(t0); p[1] = (short)f2bf(t1);
            p[2] = (short)f2bf(t2); p[3] = (short)f2bf(t3);
            p[4] = (short)f2bf(t4); p[5] = (short)f2bf(t5);
            p[6] = (short)f2bf(t6); p[7] = (short)f2bf(t7);
            bb[nt] = p;
        }
        s8v a[4];
#pragma unroll
        for (int mt = 0; mt < 4; mt++)
            a[mt] = *reinterpret_cast<const s8v*>(
                &As[(mt * 16 + lq) * 264 + h * 32 + quad * 8]);
#pragma unroll
        for (int mt = 0; mt < 4; mt++)
#pragma unroll
            for (int nt = 0; nt < 2; nt++)
                acc[mt][nt] = __builtin_amdgcn_mfma_f32_16x16x32_bf16(
                    a[mt], bb[nt], acc[mt][nt], 0, 0, 0);
    }

#pragma unroll
    for (int mt = 0; mt < 4; mt++) {
#pragma unroll
        for (int r = 0; r < 4; r++) {
            int mm = m0 + mt * 16 + quad * 4 + r;
            float bias = (mm < 32) ? bq[mm] : (mm < 64 ? bk[mm - 32] : bv[mm - 64]);
#pragma unroll
            for (int nt = 0; nt < 2; nt++) {
                int n = n0 + wave * 32 + nt * 16 + lq;
                float val = acc[mt][nt][r] + bias;
                if (mm < 32) val *= L2E;
                ushort_t obf = f2bf(val);
                if (mm < 32)
                    qw[((size_t)b * NN + n) * CKD + mm] = obf;
                else if (mm < 64)
                    kw[((size_t)b * NN + n) * CKD + (mm - 32)] = obf;
                else
                    vw[((size_t)b * CC + (mm - 64)) * NN + n] = obf;
            }
        }
    }
}

// ---------------- flash attention v3: in-register P via K-row permutation ----------------
// QK^T as mfma(K_perm, Q): loading kf[nt] row m from key rho(16nt+m), with rho the bit
// permutation out[4,3,2]=in[3,2,4], makes lane (lq,quad) hold exactly P[32s+8quad+j][q=lq]
// -- i.e. P lands DIRECTLY in A-fragment layout for PV. No LDS round-trip, no cross-lane
// ops, no per-kt barrier for P. Each wave owns 16 q rows x all 256 channels.
// V tile (64 keys) is double-buffered in LDS for rows 0..191 (shared by all 8 waves; the
// only remaining barrier, and its vmcnt(0) drain is cheap: all outstanding globals were
// issued a full iteration earlier); rows 192..255 read directly from L2 to balance the
// DS pipe (~85B/cy/CU) against L2 (~56B/cy/CU).
// grid (N/128, B), block 512 = 8 waves; 2 blocks/CU (LDS 54KB), 16 waves/CU.
#define VROWS 192
#define VSTR  72    // LDS row stride in shorts: dword bank = 4(lq+quad) -> b128-optimal

__global__ __launch_bounds__(512, 4) void attn(
    const ushort_t* __restrict__ qw, const ushort_t* __restrict__ kw,
    const ushort_t* __restrict__ vw, const float* __restrict__ x,
    const float* __restrict__ alpha, float* __restrict__ out)
{
    __shared__ __align__(16) ushort_t Vl[2][VROWS * VSTR];   // 2 x 27648 B

    int b = blockIdx.y;
    int q0 = blockIdx.x * 128;
    int tid = threadIdx.x;
    int wq = tid >> 6, lane = tid & 63;
    int lq = lane & 15, quad = lane >> 4;

    const ushort_t* kbase = kw + (size_t)b * NN * CKD;
    const ushort_t* vbase = vw + (size_t)b * CC * NN;

    // V staging assignment: thread stages rows sc, sc+64, sc+128 at key seg sseg
    int sc = tid >> 3;
    int sseg = (tid & 7) * 8;
    const ushort_t* vsrc = vbase + (size_t)sc * NN + sseg;

    // permuted K row byte-offsets: kidx(nt,lq) = 32(nt>>1) + 2(lq&12) + 4(nt&1) + (lq&3)
    int kro[4];
#pragma unroll
    for (int nt = 0; nt < 4; nt++)
        kro[nt] = (32 * (nt >> 1) + 2 * (lq & 12) + 4 * (nt & 1) + (lq & 3)) * CKD + quad * 8;

    // Q B-fragment for this wave's 16 rows
    const s8v qf = *reinterpret_cast<const s8v*>(
        qw + ((size_t)b * NN + q0 + wq * 16 + lq) * CKD + quad * 8);

    f4v acc[16];
#pragma unroll
    for (int i = 0; i < 16; i++) acc[i] = (f4v){0.f, 0.f, 0.f, 0.f};
    float srow = 0.f;

    // prologue: V[0] -> buf0; V[1] -> regs; K[0] -> kf
    s8v vr0 = *reinterpret_cast<const s8v*>(vsrc);
    s8v vr1 = *reinterpret_cast<const s8v*>(vsrc + (size_t)64 * NN);
    s8v vr2 = *reinterpret_cast<const s8v*>(vsrc + (size_t)128 * NN);
    s8v kf0 = *reinterpret_cast<const s8v*>(kbase + kro[0]);
    s8v kf1 = *reinterpret_cast<const s8v*>(kbase + kro[1]);
    s8v kf2 = *reinterpret_cast<const s8v*>(kbase + kro[2]);
    s8v kf3 = *reinterpret_cast<const s8v*>(kbase + kro[3]);
    *reinterpret_cast<s8v*>(&Vl[0][sc * VSTR + sseg]) = vr0;
    *reinterpret_cast<s8v*>(&Vl[0][(sc + 64) * VSTR + sseg]) = vr1;
    *reinterpret_cast<s8v*>(&Vl[0][(sc + 128) * VSTR + sseg]) = vr2;
    vr0 = *reinterpret_cast<const s8v*>(vsrc + 64);
    vr1 = *reinterpret_cast<const s8v*>(vsrc + (size_t)64 * NN + 64);
    vr2 = *reinterpret_cast<const s8v*>(vsrc + (size_t)128 * NN + 64);
    __syncthreads();

    for (int kt = 0; kt < 64; kt++) {
        const int kb = kt * 64;
        const int rb = kt & 1;
        const ushort_t* Vr = &Vl[rb][0];
        ushort_t* Vw = &Vl[rb ^ 1][0];

        // ---- QK^T + P fully in-register (keys pre-permuted via kro) ----
        s8v pa0, pa1;
        {
            f4v sA = __builtin_amdgcn_mfma_f32_16x16x32_bf16(kf0, qf, (f4v){0.f,0.f,0.f,0.f}, 0, 0, 0);
            f4v sB = __builtin_amdgcn_mfma_f32_16x16x32_bf16(kf1, qf, (f4v){0.f,0.f,0.f,0.f}, 0, 0, 0);
            float a0 = exp2_hw(sA[0]), a1 = exp2_hw(sA[1]), a2 = exp2_hw(sA[2]), a3 = exp2_hw(sA[3]);
            float b0 = exp2_hw(sB[0]), b1 = exp2_hw(sB[1]), b2 = exp2_hw(sB[2]), b3 = exp2_hw(sB[3]);
            srow += ((a0 + a1) + (a2 + a3)) + ((b0 + b1) + (b2 + b3));
            union { u4v u; s8v s; } t;
            t.u[0] = pkbf(a0, a1); t.u[1] = pkbf(a2, a3);
            t.u[2] = pkbf(b0, b1); t.u[3] = pkbf(b2, b3);
            pa0 = t.s;
        }
        {
            f4v sA = __builtin_amdgcn_mfma_f32_16x16x32_bf16(kf2, qf, (f4v){0.f,0.f,0.f,0.f}, 0, 0, 0);
            f4v sB = __builtin_amdgcn_mfma_f32_16x16x32_bf16(kf3, qf, (f4v){0.f,0.f,0.f,0.f}, 0, 0, 0);
            float a0 = exp2_hw(sA[0]), a1 = exp2_hw(sA[1]), a2 = exp2_hw(sA[2]), a3 = exp2_hw(sA[3]);
            float b0 = exp2_hw(sB[0]), b1 = exp2_hw(sB[1]), b2 = exp2_hw(sB[2]), b3 = exp2_hw(sB[3]);
            srow += ((a0 + a1) + (a2 + a3)) + ((b0 + b1) + (b2 + b3));
            union { u4v u; s8v s; } t;
            t.u[0] = pkbf(a0, a1); t.u[1] = pkbf(a2, a3);
            t.u[2] = pkbf(b0, b1); t.u[3] = pkbf(b2, b3);
            pa1 = t.s;
        }

        __syncthreads();                       // V double-buffer handoff (drain is stale-only)
        __builtin_amdgcn_sched_barrier(0);     // keep the loads below from hoisting above it

        // ---- stage V[kt+1] -> Vw (regs loaded one full iteration ago) ----
        *reinterpret_cast<s8v*>(&Vw[sc * VSTR + sseg]) = vr0;
        *reinterpret_cast<s8v*>(&Vw[(sc + 64) * VSTR + sseg]) = vr1;
        *reinterpret_cast<s8v*>(&Vw[(sc + 128) * VSTR + sseg]) = vr2;

        // ---- issue next-tile globals (drained at NEXT barrier, a full iter away) ----
        {
            int kn2 = (kt + 2 < 64 ? kt + 2 : 63) * 64;
            vr0 = *reinterpret_cast<const s8v*>(vsrc + kn2);
            vr1 = *reinterpret_cast<const s8v*>(vsrc + (size_t)64 * NN + kn2);
            vr2 = *reinterpret_cast<const s8v*>(vsrc + (size_t)128 * NN + kn2);
            int kn1 = (kt + 1 < 64 ? kt + 1 : 63) * 64 * CKD;
            kf0 = *reinterpret_cast<const s8v*>(kbase + kn1 + kro[0]);
            kf1 = *reinterpret_cast<const s8v*>(kbase + kn1 + kro[1]);
            kf2 = *reinterpret_cast<const s8v*>(kbase + kn1 + kro[2]);
            kf3 = *reinterpret_cast<const s8v*>(kbase + kn1 + kro[3]);
        }

        // ---- PV: LDS rows (ct 0..11), then L2-direct rows (ct 12..15) ----
        __builtin_amdgcn_s_setprio(1);
#pragma unroll
        for (int ct = 0; ct < 12; ct++) {
            s8v vb0 = *reinterpret_cast<const s8v*>(&Vr[(ct * 16 + lq) * VSTR + quad * 8]);
            s8v vb1 = *reinterpret_cast<const s8v*>(&Vr[(ct * 16 + lq) * VSTR + 32 + quad * 8]);
            acc[ct] = __builtin_amdgcn_mfma_f32_16x16x32_bf16(pa0, vb0, acc[ct], 0, 0, 0);
            acc[ct] = __builtin_amdgcn_mfma_f32_16x16x32_bf16(pa1, vb1, acc[ct], 0, 0, 0);
        }
#pragma unroll
        for (int ctg = 0; ctg < 4; ctg++) {
            size_t vrow = (size_t)(192 + ctg * 16 + lq) * NN + kb;
            s8v vg0 = *reinterpret_cast<const s8v*>(vbase + vrow + quad * 8);
            s8v vg1 = *reinterpret_cast<const s8v*>(vbase + vrow + 32 + quad * 8);
            acc[12 + ctg] = __builtin_amdgcn_mfma_f32_16x16x32_bf16(pa0, vg0, acc[12 + ctg], 0, 0, 0);
            acc[12 + ctg] = __builtin_amdgcn_mfma_f32_16x16x32_bf16(pa1, vg1, acc[12 + ctg], 0, 0, 0);
        }
        __builtin_amdgcn_s_setprio(0);
    }

    // ---- row sums: lane holds partial for q=lq; reduce across quads, then fetch per-row ----
    srow += __shfl_xor(srow, 16, 64);
    srow += __shfl_xor(srow, 32, 64);
    float li[4];
#pragma unroll
    for (int r = 0; r < 4; r++) li[r] = 1.0f / __shfl(srow, quad * 4 + r, 64);

    // ---- epilogue: out = alpha * (O / l) + x ----
    float a0 = alpha[0];
#pragma unroll
    for (int ct = 0; ct < 16; ct++) {
        int c = ct * 16 + lq;
        size_t idx = ((size_t)b * CC + c) * NN + q0 + wq * 16 + quad * 4;
        f4v xv = *reinterpret_cast<const f4v*>(x + idx);
        f4v o;
#pragma unroll
        for (int r = 0; r < 4; r++) o[r] = a0 * (acc[ct][r] * li[r]) + xv[r];
        *reinterpret_cast<f4v*>(out + idx) = o;
    }
}

extern "C" void kernel_launch(void* const* d_in, const int* in_sizes, int n_in,
                              void* d_out, int out_size, void* d_ws, size_t ws_size,
                              hipStream_t stream) {
    (void)in_sizes; (void)n_in; (void)out_size; (void)ws_size;
    const float* x     = (const float*)d_in[0];
    const float* Wq    = (const float*)d_in[1];
    const float* bq    = (const float*)d_in[2];
    const float* Wk    = (const float*)d_in[3];
    const float* bk    = (const float*)d_in[4];
    const float* Wv    = (const float*)d_in[5];
    const float* bv    = (const float*)d_in[6];
    const float* alpha = (const float*)d_in[7];
    float* out = (float*)d_out;

    // Workspace: q (4MB) | k (4MB) | v (32MB), all bf16
    char* ws = (char*)d_ws;
    ushort_t* qw = (ushort_t*)ws;
    ushort_t* kw = (ushort_t*)(ws + (size_t)BN * NN * CKD * 2);
    ushort_t* vw = (ushort_t*)(ws + (size_t)2 * BN * NN * CKD * 2);

    proj_all<<<dim3(NN / 128, 5, BN), 256, 0, stream>>>(x, Wq, bq, Wk, bk, Wv, bv, qw, kw, vw);
    attn    <<<dim3(NN / 128, BN), 512, 0, stream>>>(qw, kw, vw, x, alpha, out);
}

// Round 3
// 326.367 us; speedup vs baseline: 1.6053x; 1.6053x over previous
//
#include <hip/hip_runtime.h>
#include <cstdint>
#include <cstddef>

// Problem constants (from reference setup_inputs)
#define BN 16     // batch
#define CC 256    // channels
#define CKD 32    // q/k channels
#define NN 4096   // H*W

typedef __attribute__((ext_vector_type(8))) short s8v;    // 8 bf16 = 4 VGPRs (MFMA A/B frag)
typedef __attribute__((ext_vector_type(4))) float f4v;    // MFMA C/D frag
typedef __attribute__((ext_vector_type(4))) unsigned int u4v;
typedef __attribute__((ext_vector_type(2))) unsigned int u2v;
typedef unsigned short ushort_t;

#define L2E 1.44269504088896340736f

__device__ __forceinline__ ushort_t f2bf(float f) {
    union { float f; uint32_t u; } v; v.f = f;
    uint32_t u = v.u + 0x7FFFu + ((v.u >> 16) & 1u);  // RNE
    return (ushort_t)(u >> 16);
}
__device__ __forceinline__ uint32_t fbits(float f) {
    union { float f; uint32_t u; } v; v.f = f; return v.u;
}
// raw v_exp_f32: computes 2^x (q is pre-scaled by log2e in proj)
__device__ __forceinline__ float exp2_hw(float x) {
    float r; asm("v_exp_f32 %0, %1" : "=v"(r) : "v"(x)); return r;
}
// pack two floats to (bf16(lo) | bf16(hi)<<16), truncation
__device__ __forceinline__ uint32_t pkbf(float lo, float hi) {
    return __builtin_amdgcn_perm(fbits(hi), fbits(lo), 0x07060302u);
}

// ---------------- fused q/k/v projection as one MFMA GEMM (unchanged from v2) ----------------
__global__ __launch_bounds__(256) void proj_all(
    const float* __restrict__ x,
    const float* __restrict__ Wq, const float* __restrict__ bq,
    const float* __restrict__ Wk, const float* __restrict__ bk,
    const float* __restrict__ Wv, const float* __restrict__ bv,
    ushort_t* __restrict__ qw, ushort_t* __restrict__ kw, ushort_t* __restrict__ vw)
{
    __shared__ __align__(16) ushort_t As[64 * 264];

    int b  = blockIdx.z;
    int m0 = blockIdx.y * 64;
    int n0 = blockIdx.x * 128;
    int tid = threadIdx.x;
    int wave = tid >> 6, lane = tid & 63;
    int lq = lane & 15, quad = lane >> 4;

    {
        int arow = tid >> 2;
        int kseg = (tid & 3) * 64;
        int am = m0 + arow;
        const float* wrow;
        if (am < 32)       wrow = Wq + (size_t)am * CC;
        else if (am < 64)  wrow = Wk + (size_t)(am - 32) * CC;
        else               wrow = Wv + (size_t)(am - 64) * CC;
#pragma unroll
        for (int g = 0; g < 8; g++) {
            f4v f0 = *reinterpret_cast<const f4v*>(wrow + kseg + g * 8);
            f4v f1 = *reinterpret_cast<const f4v*>(wrow + kseg + g * 8 + 4);
            s8v p;
            p[0] = (short)f2bf(f0[0]); p[1] = (short)f2bf(f0[1]);
            p[2] = (short)f2bf(f0[2]); p[3] = (short)f2bf(f0[3]);
            p[4] = (short)f2bf(f1[0]); p[5] = (short)f2bf(f1[1]);
            p[6] = (short)f2bf(f1[2]); p[7] = (short)f2bf(f1[3]);
            *reinterpret_cast<s8v*>(&As[arow * 264 + kseg + g * 8]) = p;
        }
    }
    __syncthreads();

    f4v acc[4][2];
#pragma unroll
    for (int i = 0; i < 4; i++)
#pragma unroll
        for (int j = 0; j < 2; j++) acc[i][j] = (f4v){0.f, 0.f, 0.f, 0.f};

    const float* xb = x + (size_t)b * CC * NN + n0 + wave * 32 + lq;

#pragma unroll 2
    for (int h = 0; h < 8; h++) {
        s8v bb[2];
#pragma unroll
        for (int nt = 0; nt < 2; nt++) {
            const float* src = xb + (size_t)(h * 32 + quad * 8) * NN + nt * 16;
            float t0 = src[0 * NN];
            float t1 = src[1 * NN];
            float t2 = src[2 * NN];
            float t3 = src[3 * NN];
            float t4 = src[4 * NN];
            float t5 = src[5 * NN];
            float t6 = src[6 * NN];
            float t7 = src[7 * NN];
            s8v p;
            p[0] = (short)f2bf(t0); p[1] = (short)f2bf(t1);
            p[2] = (short)f2bf(t2); p[3] = (short)f2bf(t3);
            p[4] = (short)f2bf(t4); p[5] = (short)f2bf(t5);
            p[6] = (short)f2bf(t6); p[7] = (short)f2bf(t7);
            bb[nt] = p;
        }
        s8v a[4];
#pragma unroll
        for (int mt = 0; mt < 4; mt++)
            a[mt] = *reinterpret_cast<const s8v*>(
                &As[(mt * 16 + lq) * 264 + h * 32 + quad * 8]);
#pragma unroll
        for (int mt = 0; mt < 4; mt++)
#pragma unroll
            for (int nt = 0; nt < 2; nt++)
                acc[mt][nt] = __builtin_amdgcn_mfma_f32_16x16x32_bf16(
                    a[mt], bb[nt], acc[mt][nt], 0, 0, 0);
    }

#pragma unroll
    for (int mt = 0; mt < 4; mt++) {
#pragma unroll
        for (int r = 0; r < 4; r++) {
            int mm = m0 + mt * 16 + quad * 4 + r;
            float bias = (mm < 32) ? bq[mm] : (mm < 64 ? bk[mm - 32] : bv[mm - 64]);
#pragma unroll
            for (int nt = 0; nt < 2; nt++) {
                int n = n0 + wave * 32 + nt * 16 + lq;
                float val = acc[mt][nt][r] + bias;
                if (mm < 32) val *= L2E;
                ushort_t obf = f2bf(val);
                if (mm < 32)
                    qw[((size_t)b * NN + n) * CKD + mm] = obf;
                else if (mm < 64)
                    kw[((size_t)b * NN + n) * CKD + (mm - 32)] = obf;
                else
                    vw[((size_t)b * CC + (mm - 64)) * NN + n] = obf;
            }
        }
    }
}

// ---------------- flash attention v4: fabric-traffic-minimal ----------------
// Model fit over v1/v2/v3: attn time == (L2/L3 fabric bytes)/9.4TB/s. v4 minimizes bytes:
// Block = 128 q-rows, 8 waves. Wave w: softmax for q rows [w*16,+16) via the K-row-
// permutation trick (P lands in A-frag layout in registers, verified v3), then writes P to
// LDS (2 b128) for cross-wave PV; PV over a PRIVATE 32-channel slice x all 128 q.
//  - V: each wave reads only its 32x64 slice from global -> 32KB/block-kt, read-once.
//  - K: reg-staged into LDS once (4KB/kt, pipeline depth 3) instead of 8x-redundant reads.
//  - P: 16KB/kt through LDS (the small tensor takes the broadcast amplification).
// Fabric/kt/block: 36KB vs v2's 96KB per 128 q -> 2.6x cut. All LDS ops at bank 4*(lq+quad)
// (minimal). grid (32,16)=512 blocks, 2/CU, 16 waves/CU.
__global__ __launch_bounds__(512, 4) void attn(
    const ushort_t* __restrict__ qw, const ushort_t* __restrict__ kw,
    const ushort_t* __restrict__ vw, const float* __restrict__ x,
    const float* __restrict__ alpha, float* __restrict__ out)
{
    __shared__ __align__(16) ushort_t Pl[2][128 * 72];   // 36,864 B  P double buffer
    __shared__ __align__(16) ushort_t Kl[2][64 * 32];    //  8,192 B  K tile double buffer
    __shared__ float lL[128];                            // row denominators

    int b = blockIdx.y;
    int q0 = blockIdx.x * 128;
    int tid = threadIdx.x;
    int wq = tid >> 6, lane = tid & 63;
    int lq = lane & 15, quad = lane >> 4;

    const ushort_t* kbase = kw + (size_t)b * NN * CKD;
    const ushort_t* vbase = vw + (size_t)b * CC * NN;

    // K staging assignment: thread stages 8B of row krow at col kcol
    int krow = tid >> 3;            // 0..63
    int kcol = (tid & 7) * 4;       // shorts
    const ushort_t* ksrc = kbase + (size_t)krow * CKD + kcol;

    // permuted K-row frag offsets in Kl (shorts): kidx = 32(nt>>1)+2(lq&12)+4(nt&1)+(lq&3)
    int kro[4];
#pragma unroll
    for (int nt = 0; nt < 4; nt++)
        kro[nt] = (32 * (nt >> 1) + 2 * (lq & 12) + 4 * (nt & 1) + (lq & 3)) * 32 + quad * 8;

    // V slice rows for this wave: c = wq*32 + ct*16 + lq
    const ushort_t* vrow0 = vbase + (size_t)(wq * 32 + lq) * NN;
    const ushort_t* vrow1 = vbase + (size_t)(wq * 32 + 16 + lq) * NN;

    // Q B-fragment for this wave's 16 rows
    const s8v qf = *reinterpret_cast<const s8v*>(
        qw + ((size_t)b * NN + q0 + wq * 16 + lq) * CKD + quad * 8);

    f4v acc[8][2];
#pragma unroll
    for (int i = 0; i < 8; i++) {
        acc[i][0] = (f4v){0.f, 0.f, 0.f, 0.f};
        acc[i][1] = (f4v){0.f, 0.f, 0.f, 0.f};
    }
    float srow = 0.f;

    // ---- prologue: stage K[0],K[1]; prefetch K[2] + V[0] frags ----
    u2v k0 = *reinterpret_cast<const u2v*>(ksrc);
    u2v k1 = *reinterpret_cast<const u2v*>(ksrc + (size_t)64 * CKD);
    u2v kst = *reinterpret_cast<const u2v*>(ksrc + (size_t)128 * CKD);
    s8v v00 = *reinterpret_cast<const s8v*>(vrow0 + quad * 8);
    s8v v01 = *reinterpret_cast<const s8v*>(vrow0 + 32 + quad * 8);
    s8v v10 = *reinterpret_cast<const s8v*>(vrow1 + quad * 8);
    s8v v11 = *reinterpret_cast<const s8v*>(vrow1 + 32 + quad * 8);
    *reinterpret_cast<u2v*>(&Kl[0][krow * 32 + kcol]) = k0;
    *reinterpret_cast<u2v*>(&Kl[1][krow * 32 + kcol]) = k1;
    __syncthreads();

    for (int kt = 0; kt < 64; kt++) {
        const int cur = kt & 1;

        // ---- QK^T from Kl[cur]; P in-register via permuted rows (v3-verified) ----
        s8v pa0, pa1;
        {
            s8v kf0 = *reinterpret_cast<const s8v*>(&Kl[cur][kro[0]]);
            s8v kf1 = *reinterpret_cast<const s8v*>(&Kl[cur][kro[1]]);
            f4v sA = __builtin_amdgcn_mfma_f32_16x16x32_bf16(kf0, qf, (f4v){0.f,0.f,0.f,0.f}, 0, 0, 0);
            f4v sB = __builtin_amdgcn_mfma_f32_16x16x32_bf16(kf1, qf, (f4v){0.f,0.f,0.f,0.f}, 0, 0, 0);
            s8v kf2 = *reinterpret_cast<const s8v*>(&Kl[cur][kro[2]]);
            s8v kf3 = *reinterpret_cast<const s8v*>(&Kl[cur][kro[3]]);
            f4v sC = __builtin_amdgcn_mfma_f32_16x16x32_bf16(kf2, qf, (f4v){0.f,0.f,0.f,0.f}, 0, 0, 0);
            f4v sD = __builtin_amdgcn_mfma_f32_16x16x32_bf16(kf3, qf, (f4v){0.f,0.f,0.f,0.f}, 0, 0, 0);
            float a0 = exp2_hw(sA[0]), a1 = exp2_hw(sA[1]), a2 = exp2_hw(sA[2]), a3 = exp2_hw(sA[3]);
            float b0 = exp2_hw(sB[0]), b1 = exp2_hw(sB[1]), b2 = exp2_hw(sB[2]), b3 = exp2_hw(sB[3]);
            srow += ((a0 + a1) + (a2 + a3)) + ((b0 + b1) + (b2 + b3));
            union { u4v u; s8v s; } t0;
            t0.u[0] = pkbf(a0, a1); t0.u[1] = pkbf(a2, a3);
            t0.u[2] = pkbf(b0, b1); t0.u[3] = pkbf(b2, b3);
            pa0 = t0.s;
            float c0 = exp2_hw(sC[0]), c1 = exp2_hw(sC[1]), c2 = exp2_hw(sC[2]), c3 = exp2_hw(sC[3]);
            float d0 = exp2_hw(sD[0]), d1 = exp2_hw(sD[1]), d2 = exp2_hw(sD[2]), d3 = exp2_hw(sD[3]);
            srow += ((c0 + c1) + (c2 + c3)) + ((d0 + d1) + (d2 + d3));
            union { u4v u; s8v s; } t1;
            t1.u[0] = pkbf(c0, c1); t1.u[1] = pkbf(c2, c3);
            t1.u[2] = pkbf(d0, d1); t1.u[3] = pkbf(d2, d3);
            pa1 = t1.s;
        }

        // publish P (same (row,col) the A-frag reads use -> identity round-trip)
        {
            int prow = (wq * 16 + lq) * 72;
            *reinterpret_cast<s8v*>(&Pl[cur][prow + quad * 8]) = pa0;
            *reinterpret_cast<s8v*>(&Pl[cur][prow + 32 + quad * 8]) = pa1;
        }

        __syncthreads();
        __builtin_amdgcn_sched_barrier(0);

        // stage K[kt+2] -> Kl[cur] (reads of Kl[cur] finished pre-barrier; next read kt+2)
        *reinterpret_cast<u2v*>(&Kl[cur][krow * 32 + kcol]) = kst;

        // ---- PV: O += P V^T over this wave's 32-c slice, all 128 q ----
        __builtin_amdgcn_s_setprio(1);
#pragma unroll
        for (int qt = 0; qt < 8; qt++) {
            s8v pA0 = *reinterpret_cast<const s8v*>(&Pl[cur][(qt * 16 + lq) * 72 + quad * 8]);
            s8v pA1 = *reinterpret_cast<const s8v*>(&Pl[cur][(qt * 16 + lq) * 72 + 32 + quad * 8]);
            acc[qt][0] = __builtin_amdgcn_mfma_f32_16x16x32_bf16(pA0, v00, acc[qt][0], 0, 0, 0);
            acc[qt][0] = __builtin_amdgcn_mfma_f32_16x16x32_bf16(pA1, v01, acc[qt][0], 0, 0, 0);
            acc[qt][1] = __builtin_amdgcn_mfma_f32_16x16x32_bf16(pA0, v10, acc[qt][1], 0, 0, 0);
            acc[qt][1] = __builtin_amdgcn_mfma_f32_16x16x32_bf16(pA1, v11, acc[qt][1], 0, 0, 0);
        }
        __builtin_amdgcn_s_setprio(0);

        // ---- next-tile loads (cover: next QK+exp+P-write+barrier) ----
        {
            int kbn = (kt + 1 < 64 ? kt + 1 : 63) * 64;
            v00 = *reinterpret_cast<const s8v*>(vrow0 + kbn + quad * 8);
            v01 = *reinterpret_cast<const s8v*>(vrow0 + kbn + 32 + quad * 8);
            v10 = *reinterpret_cast<const s8v*>(vrow1 + kbn + quad * 8);
            v11 = *reinterpret_cast<const s8v*>(vrow1 + kbn + 32 + quad * 8);
            int kn = (kt + 3 < 64 ? kt + 3 : 63) * 64;
            kst = *reinterpret_cast<const u2v*>(ksrc + (size_t)kn * CKD);
        }
    }

    // ---- row sums: reduce across quads; share per-wave via LDS ----
    srow += __shfl_xor(srow, 16, 64);
    srow += __shfl_xor(srow, 32, 64);
    if (quad == 0) lL[wq * 16 + lq] = srow;
    __syncthreads();

    // ---- epilogue: out = alpha * (O / l) + x ----
    float a0 = alpha[0];
#pragma unroll
    for (int qt = 0; qt < 8; qt++) {
        float li[4];
#pragma unroll
        for (int r = 0; r < 4; r++) li[r] = 1.0f / lL[qt * 16 + quad * 4 + r];
#pragma unroll
        for (int ct = 0; ct < 2; ct++) {
            int c = wq * 32 + ct * 16 + lq;
            size_t idx = ((size_t)b * CC + c) * NN + q0 + qt * 16 + quad * 4;
            f4v xv = *reinterpret_cast<const f4v*>(x + idx);
            f4v o;
#pragma unroll
            for (int r = 0; r < 4; r++) o[r] = a0 * (acc[qt][ct][r] * li[r]) + xv[r];
            *reinterpret_cast<f4v*>(out + idx) = o;
        }
    }
}

extern "C" void kernel_launch(void* const* d_in, const int* in_sizes, int n_in,
                              void* d_out, int out_size, void* d_ws, size_t ws_size,
                              hipStream_t stream) {
    (void)in_sizes; (void)n_in; (void)out_size; (void)ws_size;
    const float* x     = (const float*)d_in[0];
    const float* Wq    = (const float*)d_in[1];
    const float* bq    = (const float*)d_in[2];
    const float* Wk    = (const float*)d_in[3];
    const float* bk    = (const float*)d_in[4];
    const float* Wv    = (const float*)d_in[5];
    const float* bv    = (const float*)d_in[6];
    const float* alpha = (const float*)d_in[7];
    float* out = (float*)d_out;

    // Workspace: q (4MB) | k (4MB) | v (32MB), all bf16
    char* ws = (char*)d_ws;
    ushort_t* qw = (ushort_t*)ws;
    ushort_t* kw = (ushort_t*)(ws + (size_t)BN * NN * CKD * 2);
    ushort_t* vw = (ushort_t*)(ws + (size_t)2 * BN * NN * CKD * 2);

    proj_all<<<dim3(NN / 128, 5, BN), 256, 0, stream>>>(x, Wq, bq, Wk, bk, Wv, bv, qw, kw, vw);
    attn    <<<dim3(NN / 128, BN), 512, 0, stream>>>(qw, kw, vw, x, alpha, out);
}